// Round 9
// baseline (389.250 us; speedup 1.0000x reference)
//
#include <hip/hip_runtime.h>
#include <hip/hip_fp16.h>
#include <math.h>

#define N_NODESc 100000
#define N_EDGESc 800000
#define E_TOTc   (N_EDGESc + N_NODESc)   // 900000, includes self loops
#define F_INc    128
#define HC1c     256                      // H1*C1
#define NCLSc    40
#define NEG_SLOPEc 0.2f

typedef _Float16 half8 __attribute__((ext_vector_type(8)));   // MFMA A/B frag
typedef __fp16   f16x2 __attribute__((ext_vector_type(2)));   // v_pk_* / cvt_pkrtz
typedef float    f32x4 __attribute__((ext_vector_type(4)));

__device__ __forceinline__ f16x2 shfl_xor_h2(f16x2 v, int mask) {
    union { f16x2 h; int i; } u; u.h = v;
    u.i = __shfl_xor(u.i, mask);
    return u.h;
}

// ---------------- CSR build ----------------

// fused: blocks [0,22) swizzle weights into MFMA B-fragment order; rest count.
__global__ void k_prep_count(const float* __restrict__ W1, const float* __restrict__ W2,
                             _Float16* __restrict__ W1Tf, _Float16* __restrict__ W2Tf,
                             const int* __restrict__ dst, int* cnt) {
    if (blockIdx.x < 22) {
        int f = blockIdx.x * 256 + threadIdx.x;
        if (f < 4096) {
            int lane16 = f & 15, quad = (f >> 4) & 3, k0 = (f >> 6) & 3, jt = f >> 8;
            int c = lane16 * 16 + jt;
            int kbase = k0 * 32 + quad * 8;
            _Float16* o = W1Tf + (size_t)f * 8;
            #pragma unroll
            for (int j = 0; j < 8; j++) o[j] = (_Float16)W1[(kbase + j) * HC1c + c];
        } else if (f < 4096 + 1536) {
            int g = f - 4096;
            int lane16 = g & 15, quad = (g >> 4) & 3, k0 = (g >> 6) & 7, jt = g >> 9;
            int c = jt * 16 + lane16;
            int kbase = k0 * 32 + quad * 8;
            _Float16* o = W2Tf + (size_t)g * 8;
            #pragma unroll
            for (int j = 0; j < 8; j++)
                o[j] = (c < NCLSc) ? (_Float16)W2[(kbase + j) * NCLSc + c] : (_Float16)0.f;
        }
    } else {
        int i = (blockIdx.x - 22) * 256 + threadIdx.x;   // 2 edges / thread
        if (i < N_EDGESc / 2) {
            int2 d = ((const int2*)dst)[i];
            atomicAdd(&cnt[d.x], 1);
            atomicAdd(&cnt[d.y], 1);
        }
    }
}

__global__ void k_scan1(const int* __restrict__ cnt, int* rowptr, int* bsums) {
    __shared__ int sh[512];
    int tid = threadIdx.x;
    int i = blockIdx.x * 512 + tid;
    int v = (i < N_NODESc) ? (cnt[i] + 1) : 0;   // +1 = self loop
    sh[tid] = v;
    __syncthreads();
    for (int off = 1; off < 512; off <<= 1) {
        int t = (tid >= off) ? sh[tid - off] : 0;
        __syncthreads();
        sh[tid] += t;
        __syncthreads();
    }
    if (i < N_NODESc) rowptr[i] = sh[tid] - v;
    if (tid == 511) bsums[blockIdx.x] = sh[511];
}

// one wave, shuffle prefix scan over nb (<=512) block sums
__global__ void k_scan2(int* bsums, int nb) {
    int L = threadIdx.x;          // 64 threads
    int run = 0;
    for (int s = 0; s < nb; s += 64) {
        int idx = s + L;
        int o = (idx < nb) ? bsums[idx] : 0;
        int v = o;
        #pragma unroll
        for (int off = 1; off < 64; off <<= 1) {
            int t = __shfl_up(v, off);
            if (L >= off) v += t;
        }
        int total = __shfl(v, 63);
        if (idx < nb) bsums[idx] = run + v - o;   // exclusive
        run += total;
    }
}

__global__ void k_scan3(int* rowptr, const int* __restrict__ bsums, int* cursor,
                        int* csr) {
    int i = blockIdx.x * blockDim.x + threadIdx.x;
    if (i < N_NODESc) {
        int rp = rowptr[i] + bsums[i >> 9];
        rowptr[i] = rp;
        cursor[i] = rp + 1;      // slot rp taken by the self loop
        csr[rp] = i;
    }
    if (i == 0) rowptr[N_NODESc] = E_TOTc;
}

__global__ void k_scatter(const int* __restrict__ src, const int* __restrict__ dst,
                          int* cursor, int* csr) {
    int i = blockIdx.x * blockDim.x + threadIdx.x;   // 2 edges / thread
    if (i < N_EDGESc / 2) {
        int2 s = ((const int2*)src)[i];
        int2 d = ((const int2*)dst)[i];
        int p0 = atomicAdd(&cursor[d.x], 1);
        csr[p0] = s.x;
        int p1 = atomicAdd(&cursor[d.y], 1);
        csr[p1] = s.y;
    }
}

// ---------------- Layer 1 GEMM (MFMA f16): h1 = f16(x) @ W1 ------------------

__global__ __launch_bounds__(256) void k_gemm1(
    const float* __restrict__ x, const _Float16* __restrict__ W1Tf,
    const float* __restrict__ a_src1, const float* __restrict__ a_dst1,
    _Float16* __restrict__ h1, float* __restrict__ as1, float* __restrict__ ad1) {
    int wave = (blockIdx.x * 256 + threadIdx.x) >> 6;
    int n0 = wave * 16;
    if (n0 >= N_NODESc) return;
    int L = threadIdx.x & 63, lane16 = L & 15, quad = L >> 4;
    f32x4 acc[16];
    #pragma unroll
    for (int jt = 0; jt < 16; jt++) acc[jt] = (f32x4){0.f, 0.f, 0.f, 0.f};
    const float* A = x + (size_t)(n0 + lane16) * F_INc + quad * 8;
    const _Float16* Bf = W1Tf + L * 8;
    #pragma unroll
    for (int k0 = 0; k0 < 4; k0++) {                         // K = 4 x 32
        float4 f0 = *(const float4*)(A + k0 * 32);
        float4 f1 = *(const float4*)(A + k0 * 32 + 4);
        union { half8 v; f16x2 h[4]; } af;
        af.h[0] = __builtin_amdgcn_cvt_pkrtz(f0.x, f0.y);
        af.h[1] = __builtin_amdgcn_cvt_pkrtz(f0.z, f0.w);
        af.h[2] = __builtin_amdgcn_cvt_pkrtz(f1.x, f1.y);
        af.h[3] = __builtin_amdgcn_cvt_pkrtz(f1.z, f1.w);
        #pragma unroll
        for (int jt = 0; jt < 16; jt++) {
            half8 bf = *(const half8*)(Bf + (jt * 4 + k0) * 512);
            acc[jt] = __builtin_amdgcn_mfma_f32_16x16x32_f16(af.v, bf, acc[jt], 0, 0, 0);
        }
    }
    // store: row n0+quad*4+r, logical cols lane16*16..+15 (contiguous)
    {
        size_t rowbase = (size_t)(n0 + quad * 4) * HC1c + lane16 * 16;
        #pragma unroll
        for (int r = 0; r < 4; r++) {
            union { uint4 u; f16x2 h[4]; } s0, s1;
            #pragma unroll
            for (int q = 0; q < 4; q++) {
                s0.h[q] = __builtin_amdgcn_cvt_pkrtz(acc[2 * q][r], acc[2 * q + 1][r]);
                s1.h[q] = __builtin_amdgcn_cvt_pkrtz(acc[8 + 2 * q][r], acc[9 + 2 * q][r]);
            }
            *(uint4*)(h1 + rowbase + (size_t)r * HC1c) = s0.u;
            *(uint4*)(h1 + rowbase + (size_t)r * HC1c + 8) = s1.u;
        }
    }
    // alpha epilogue: lane's 16 cols all in head lane16>>1
    {
        float asv[16], adv[16];
        const float4* ap = (const float4*)(a_src1 + lane16 * 16);
        const float4* dp = (const float4*)(a_dst1 + lane16 * 16);
        #pragma unroll
        for (int q = 0; q < 4; q++) {
            float4 a4 = ap[q], d4 = dp[q];
            asv[4*q] = a4.x; asv[4*q+1] = a4.y; asv[4*q+2] = a4.z; asv[4*q+3] = a4.w;
            adv[4*q] = d4.x; adv[4*q+1] = d4.y; adv[4*q+2] = d4.z; adv[4*q+3] = d4.w;
        }
        float ps[4] = {0,0,0,0}, pd[4] = {0,0,0,0};
        #pragma unroll
        for (int jt = 0; jt < 16; jt++) {
            #pragma unroll
            for (int r = 0; r < 4; r++) {
                ps[r] += acc[jt][r] * asv[jt];
                pd[r] += acc[jt][r] * adv[jt];
            }
        }
        #pragma unroll
        for (int r = 0; r < 4; r++) {
            ps[r] += __shfl_xor(ps[r], 1);
            pd[r] += __shfl_xor(pd[r], 1);
        }
        if ((lane16 & 1) == 0) {
            int h = lane16 >> 1;
            #pragma unroll
            for (int r = 0; r < 4; r++) {
                int n = n0 + quad * 4 + r;
                as1[n * 8 + h] = ps[r];
                ad1[n * 8 + h] = pd[r];
            }
        }
    }
}

// ---------------- Layer 1 aggregation: wave-per-node ------------------------
// First chunk peeled (covers deg<=16, ~97% of nodes): no online-rescale work.
// Gather j-blocks skipped wave-uniformly when both edges absent.

__device__ __forceinline__ void agg1_gather(
    int m, int mlo, float w, int src, int half, int l32, int hA,
    const _Float16* __restrict__ h1, f16x2 acc4[4]) {
    // edges mlo.. mlo+min(m-mlo,8)-1 described by (w,src) at phase lanes e*8+hA
    #pragma unroll
    for (int j = 0; j < 4; j++) {
        if (mlo + 2 * j < m) {                       // wave-uniform
            int e = 2 * j + half;
            float we = __shfl(w, e * 8 + hA);
            int  se = __shfl(src, e * 8 + hA);
            uint4 pk = (uint4){0u, 0u, 0u, 0u};
            if (mlo + e < m)
                pk = *((const uint4*)(h1 + (size_t)se * HC1c) + l32);
            f16x2 we2 = __builtin_amdgcn_cvt_pkrtz(we, we);
            union { uint4 u; f16x2 h[4]; } pp; pp.u = pk;
            acc4[0] += we2 * pp.h[0];
            acc4[1] += we2 * pp.h[1];
            acc4[2] += we2 * pp.h[2];
            acc4[3] += we2 * pp.h[3];
        }
    }
}

__global__ __launch_bounds__(256) void k_agg1(
    const int* __restrict__ rowptr, const int* __restrict__ csr,
    const float* __restrict__ as1, const float* __restrict__ ad1,
    const _Float16* __restrict__ h1, const float* __restrict__ b1,
    _Float16* __restrict__ act1b) {
    int n = blockIdx.x * 4 + (threadIdx.x >> 6);
    if (n >= N_NODESc) return;
    int L = threadIdx.x & 63;
    int eL = L >> 3, hL = L & 7;
    int half = L >> 5, l32 = L & 31;
    int hA = l32 >> 2;
    int beg = rowptr[n], end = rowptr[n + 1];
    float ad = ad1[n * 8 + hL];
    float m_run, d_run;
    f16x2 acc4[4];
    #pragma unroll
    for (int q = 0; q < 4; q++) acc4[q] = (f16x2){(__fp16)0.f, (__fp16)0.f};
    // ---- first chunk (peeled; acc==0 so no rescale) ----
    {
        int m = min(16, end - beg);
        int src0 = 0, src1 = 0;
        float s0 = -INFINITY, s1 = -INFINITY;
        if (eL < m) {
            src0 = csr[beg + eL];
            float v = as1[src0 * 8 + hL] + ad;
            s0 = (v > 0.f) ? v : NEG_SLOPEc * v;
        }
        if (eL + 8 < m) {
            src1 = csr[beg + eL + 8];
            float v = as1[src1 * 8 + hL] + ad;
            s1 = (v > 0.f) ? v : NEG_SLOPEc * v;
        }
        float mc = fmaxf(s0, s1);
        mc = fmaxf(mc, __shfl_xor(mc, 8));
        mc = fmaxf(mc, __shfl_xor(mc, 16));
        mc = fmaxf(mc, __shfl_xor(mc, 32));
        float w0 = (eL < m) ? __expf(s0 - mc) : 0.f;
        float w1 = (eL + 8 < m) ? __expf(s1 - mc) : 0.f;
        float wsum = w0 + w1;
        wsum += __shfl_xor(wsum, 8);
        wsum += __shfl_xor(wsum, 16);
        wsum += __shfl_xor(wsum, 32);
        m_run = mc; d_run = wsum;
        agg1_gather(m, 0, w0, src0, half, l32, hA, h1, acc4);
        if (m > 8) agg1_gather(m, 8, w1, src1, half, l32, hA, h1, acc4);
    }
    // ---- rare remainder (deg > 16) ----
    for (int base = beg + 16; base < end; base += 16) {
        int m = min(16, end - base);
        int src0 = 0, src1 = 0;
        float s0 = -INFINITY, s1 = -INFINITY;
        if (eL < m) {
            src0 = csr[base + eL];
            float v = as1[src0 * 8 + hL] + ad;
            s0 = (v > 0.f) ? v : NEG_SLOPEc * v;
        }
        if (eL + 8 < m) {
            src1 = csr[base + eL + 8];
            float v = as1[src1 * 8 + hL] + ad;
            s1 = (v > 0.f) ? v : NEG_SLOPEc * v;
        }
        float mc = fmaxf(s0, s1);
        mc = fmaxf(mc, __shfl_xor(mc, 8));
        mc = fmaxf(mc, __shfl_xor(mc, 16));
        mc = fmaxf(mc, __shfl_xor(mc, 32));
        float mnew = fmaxf(m_run, mc);
        float w0 = (eL < m) ? __expf(s0 - mnew) : 0.f;
        float w1 = (eL + 8 < m) ? __expf(s1 - mnew) : 0.f;
        float wsum = w0 + w1;
        wsum += __shfl_xor(wsum, 8);
        wsum += __shfl_xor(wsum, 16);
        wsum += __shfl_xor(wsum, 32);
        float scale = __expf(m_run - mnew);
        d_run = d_run * scale + wsum;
        m_run = mnew;
        float sc = __shfl(scale, hA);
        f16x2 sc2 = __builtin_amdgcn_cvt_pkrtz(sc, sc);
        #pragma unroll
        for (int q = 0; q < 4; q++) acc4[q] *= sc2;
        agg1_gather(m, 0, w0, src0, half, l32, hA, h1, acc4);
        if (m > 8) agg1_gather(m, 8, w1, src1, half, l32, hA, h1, acc4);
    }
    float inv = 1.f / (d_run + 1e-16f);
    float inv_h = __shfl(inv, hA);
    #pragma unroll
    for (int q = 0; q < 4; q++) acc4[q] += shfl_xor_h2(acc4[q], 32);
    if (half == 0) {
        float4 b0 = ((const float4*)b1)[l32 * 2];
        float4 b4 = ((const float4*)b1)[l32 * 2 + 1];
        float o[8];
        o[0] = (float)acc4[0][0] * inv_h + b0.x; o[1] = (float)acc4[0][1] * inv_h + b0.y;
        o[2] = (float)acc4[1][0] * inv_h + b0.z; o[3] = (float)acc4[1][1] * inv_h + b0.w;
        o[4] = (float)acc4[2][0] * inv_h + b4.x; o[5] = (float)acc4[2][1] * inv_h + b4.y;
        o[6] = (float)acc4[3][0] * inv_h + b4.z; o[7] = (float)acc4[3][1] * inv_h + b4.w;
        #pragma unroll
        for (int j = 0; j < 8; j++) o[j] = (o[j] > 0.f) ? o[j] : expm1f(o[j]);
        union { uint4 u; f16x2 h[4]; } st;
        st.h[0] = __builtin_amdgcn_cvt_pkrtz(o[0], o[1]);
        st.h[1] = __builtin_amdgcn_cvt_pkrtz(o[2], o[3]);
        st.h[2] = __builtin_amdgcn_cvt_pkrtz(o[4], o[5]);
        st.h[3] = __builtin_amdgcn_cvt_pkrtz(o[6], o[7]);
        *((uint4*)(act1b + (size_t)n * HC1c) + l32) = st.u;
    }
}

// ---------------- Layer 2 GEMM (MFMA f16) + fused alpha2; h2 out = fp16 ------

__global__ __launch_bounds__(256) void k_gemm2(
    const _Float16* __restrict__ act1b, const _Float16* __restrict__ W2Tf,
    const float* __restrict__ a_src2, const float* __restrict__ a_dst2,
    _Float16* __restrict__ h2b, float* __restrict__ as2, float* __restrict__ ad2) {
    int wave = (blockIdx.x * 256 + threadIdx.x) >> 6;
    int n0 = wave * 16;
    if (n0 >= N_NODESc) return;
    int L = threadIdx.x & 63, lane16 = L & 15, quad = L >> 4;
    f32x4 acc[3];
    #pragma unroll
    for (int jt = 0; jt < 3; jt++) acc[jt] = (f32x4){0.f, 0.f, 0.f, 0.f};
    const _Float16* A = act1b + (size_t)(n0 + lane16) * HC1c + quad * 8;
    const _Float16* Bf = W2Tf + L * 8;
    #pragma unroll
    for (int k0 = 0; k0 < 8; k0++) {                         // K = 8 x 32
        half8 af = *(const half8*)(A + k0 * 32);
        #pragma unroll
        for (int jt = 0; jt < 3; jt++) {
            half8 bf = *(const half8*)(Bf + (jt * 8 + k0) * 512);
            acc[jt] = __builtin_amdgcn_mfma_f32_16x16x32_f16(af, bf, acc[jt], 0, 0, 0);
        }
    }
    float ps[4] = {0.f, 0.f, 0.f, 0.f}, pd[4] = {0.f, 0.f, 0.f, 0.f};
    #pragma unroll
    for (int jt = 0; jt < 3; jt++) {
        int col = jt * 16 + lane16;
        float ws = (col < NCLSc) ? a_src2[col] : 0.f;
        float wd = (col < NCLSc) ? a_dst2[col] : 0.f;
        #pragma unroll
        for (int r = 0; r < 4; r++) {
            float v = acc[jt][r];
            int n = n0 + quad * 4 + r;
            if (col < NCLSc) h2b[(size_t)n * NCLSc + col] = (_Float16)v;
            ps[r] += v * ws; pd[r] += v * wd;
        }
    }
    #pragma unroll
    for (int r = 0; r < 4; r++) {
        float s = ps[r], d = pd[r];
        s += __shfl_xor(s, 1); d += __shfl_xor(d, 1);
        s += __shfl_xor(s, 2); d += __shfl_xor(d, 2);
        s += __shfl_xor(s, 4); d += __shfl_xor(d, 4);
        s += __shfl_xor(s, 8); d += __shfl_xor(d, 8);
        if (lane16 == 0) {
            int n = n0 + quad * 4 + r;
            as2[n] = s; ad2[n] = d;
        }
    }
}

// ---------------- Layer 2 aggregation + bias + log_softmax: wave-per-node ----
// First chunk peeled (deg<=64: essentially all nodes).

__global__ __launch_bounds__(256) void k_agg2(
    const int* __restrict__ rowptr, const int* __restrict__ csr,
    const float* __restrict__ as2, const float* __restrict__ ad2,
    const _Float16* __restrict__ h2b, const float* __restrict__ b2,
    float* __restrict__ out) {
    int n = blockIdx.x * 4 + (threadIdx.x >> 6);
    if (n >= N_NODESc) return;
    int L = threadIdx.x & 63;
    int g = L / 20, cls = L % 20;        // g==3 for lanes 60..63 (gather-idle)
    int beg = rowptr[n], end = rowptr[n + 1];
    float ad = ad2[n];
    float m_run, d_run;
    f16x2 acc2 = (f16x2){(__fp16)0.f, (__fp16)0.f};
    {
        int m = min(64, end - beg);
        int src = 0; float s = -INFINITY;
        if (L < m) {
            src = csr[beg + L];
            float v = as2[src] + ad;
            s = (v > 0.f) ? v : NEG_SLOPEc * v;
        }
        float mc = s;
        for (int o = 32; o; o >>= 1) mc = fmaxf(mc, __shfl_xor(mc, o));
        float w = (L < m) ? __expf(s - mc) : 0.f;
        float ws = w;
        for (int o = 32; o; o >>= 1) ws += __shfl_xor(ws, o);
        m_run = mc; d_run = ws;
        for (int j = 0; j < m; j += 3) {
            int e = j + g;
            int lane = (e < 64) ? e : 63;
            float we = __shfl(w, lane);
            int  se = __shfl(src, lane);
            if (g < 3 && e < m) {
                f16x2 we2 = __builtin_amdgcn_cvt_pkrtz(we, we);
                union { unsigned u; f16x2 h; } pk;
                pk.u = *((const unsigned*)(h2b + (size_t)se * NCLSc) + cls);
                acc2 += we2 * pk.h;
            }
        }
    }
    for (int base = beg + 64; base < end; base += 64) {
        int m = min(64, end - base);
        int src = 0; float s = -INFINITY;
        if (L < m) {
            src = csr[base + L];
            float v = as2[src] + ad;
            s = (v > 0.f) ? v : NEG_SLOPEc * v;
        }
        float mc = s;
        for (int o = 32; o; o >>= 1) mc = fmaxf(mc, __shfl_xor(mc, o));
        float mnew = fmaxf(m_run, mc);
        float w = (L < m) ? __expf(s - mnew) : 0.f;
        float ws = w;
        for (int o = 32; o; o >>= 1) ws += __shfl_xor(ws, o);
        float scale = __expf(m_run - mnew);
        d_run = d_run * scale + ws;
        m_run = mnew;
        f16x2 sc2 = __builtin_amdgcn_cvt_pkrtz(scale, scale);
        acc2 *= sc2;
        for (int j = 0; j < m; j += 3) {
            int e = j + g;
            int lane = (e < 64) ? e : 63;
            float we = __shfl(w, lane);
            int  se = __shfl(src, lane);
            if (g < 3 && e < m) {
                f16x2 we2 = __builtin_amdgcn_cvt_pkrtz(we, we);
                union { unsigned u; f16x2 h; } pk;
                pk.u = *((const unsigned*)(h2b + (size_t)se * NCLSc) + cls);
                acc2 += we2 * pk.h;
            }
        }
    }
    union { f16x2 h; int i; } au; au.h = acc2;
    int i1 = __shfl(au.i, (L + 20) & 63);
    int i2 = __shfl(au.i, (L + 40) & 63);
    union { int i; f16x2 h; } b1u, b2u; b1u.i = i1; b2u.i = i2;
    acc2 = acc2 + b1u.h + b2u.h;
    float vx = -INFINITY, vy = -INFINITY;
    if (L < 20) {
        float2 bb = ((const float2*)b2)[L];
        float inv = 1.f / (d_run + 1e-16f);
        vx = (float)acc2[0] * inv + bb.x;
        vy = (float)acc2[1] * inv + bb.y;
    }
    float mv = fmaxf(vx, vy);
    for (int o = 32; o; o >>= 1) mv = fmaxf(mv, __shfl_xor(mv, o));
    float ex = (L < 20) ? __expf(vx - mv) + __expf(vy - mv) : 0.f;
    for (int o = 32; o; o >>= 1) ex += __shfl_xor(ex, o);
    float ls = logf(ex);
    if (L < 20) {
        float2 o2; o2.x = vx - mv - ls; o2.y = vy - mv - ls;
        ((float2*)(out + (size_t)n * NCLSc))[L] = o2;
    }
}

// ---------------- launch ----------------

extern "C" void kernel_launch(void* const* d_in, const int* in_sizes, int n_in,
                              void* d_out, int out_size, void* d_ws, size_t ws_size,
                              hipStream_t stream) {
    const float* x    = (const float*)d_in[0];
    const int*   ei   = (const int*)d_in[1];
    const float* W1   = (const float*)d_in[2];
    const float* as1w = (const float*)d_in[3];
    const float* ad1w = (const float*)d_in[4];
    const float* b1   = (const float*)d_in[5];
    const float* W2   = (const float*)d_in[6];
    const float* as2w = (const float*)d_in[7];
    const float* ad2w = (const float*)d_in[8];
    const float* b2   = (const float*)d_in[9];
    float* out = (float*)d_out;

    char* p = (char*)d_ws;
    _Float16* h1    = (_Float16*)p; p += (size_t)N_NODESc * HC1c * 2;
    _Float16* act1b = (_Float16*)p; p += (size_t)N_NODESc * HC1c * 2;
    _Float16* W1Tf  = (_Float16*)p; p += (size_t)4096 * 8 * 2;   // 64 KB
    _Float16* W2Tf  = (_Float16*)p; p += (size_t)1536 * 8 * 2;   // 24 KB
    float* a_s1 = (float*)p; p += (size_t)N_NODESc * 8 * 4;
    float* a_d1 = (float*)p; p += (size_t)N_NODESc * 8 * 4;
    _Float16* h2b = (_Float16*)p; p += (size_t)N_NODESc * NCLSc * 2;
    float* a_s2 = (float*)p; p += (size_t)N_NODESc * 4;
    float* a_d2 = (float*)p; p += (size_t)N_NODESc * 4;
    int* rowptr = (int*)p;   p += (size_t)(N_NODESc + 1) * 4;
    int* cursor = (int*)p;   p += (size_t)N_NODESc * 4;
    int* bsums  = (int*)p;   p += 512 * 4;
    int* csr    = (int*)p;   p += (size_t)E_TOTc * 4;
    (void)ws_size; (void)in_sizes; (void)n_in; (void)out_size;

    const int* src = ei;
    const int* dst = ei + N_EDGESc;

    // CSR build (self loops folded into scan; cursor doubles as count buffer)
    (void)hipMemsetAsync(cursor, 0, (size_t)N_NODESc * 4, stream);
    k_prep_count<<<22 + (N_EDGESc / 2 + 255) / 256, 256, 0, stream>>>(
        W1, W2, W1Tf, W2Tf, dst, cursor);
    int nb = (N_NODESc + 511) / 512;
    k_scan1<<<nb, 512, 0, stream>>>(cursor, rowptr, bsums);
    k_scan2<<<1, 64, 0, stream>>>(bsums, nb);
    k_scan3<<<(N_NODESc + 255) / 256, 256, 0, stream>>>(rowptr, bsums, cursor, csr);
    k_scatter<<<(N_EDGESc / 2 + 255) / 256, 256, 0, stream>>>(src, dst, cursor, csr);

    int nwave_blk = ((N_NODESc + 15) / 16 + 3) / 4;          // 1563
    k_gemm1<<<nwave_blk, 256, 0, stream>>>(x, W1Tf, as1w, ad1w, h1, a_s1, a_d1);
    k_agg1<<<(N_NODESc + 3) / 4, 256, 0, stream>>>(rowptr, csr, a_s1, a_d1, h1, b1, act1b);
    k_gemm2<<<nwave_blk, 256, 0, stream>>>(act1b, W2Tf, as2w, ad2w, h2b, a_s2, a_d2);
    k_agg2<<<(N_NODESc + 3) / 4, 256, 0, stream>>>(rowptr, csr, a_s2, a_d2, h2b, b2, out);
}

// Round 10
// 374.443 us; speedup vs baseline: 1.0395x; 1.0395x over previous
//
#include <hip/hip_runtime.h>
#include <hip/hip_fp16.h>
#include <math.h>

#define N_NODESc 100000
#define N_EDGESc 800000
#define E_TOTc   (N_EDGESc + N_NODESc)   // 900000, includes self loops
#define F_INc    128
#define HC1c     256                      // H1*C1
#define NCLSc    40
#define NEG_SLOPEc 0.2f

typedef _Float16 half8 __attribute__((ext_vector_type(8)));   // MFMA A/B frag
typedef __fp16   f16x2 __attribute__((ext_vector_type(2)));   // v_pk_* / cvt_pkrtz
typedef float    f32x4 __attribute__((ext_vector_type(4)));

__device__ __forceinline__ f16x2 shfl_xor_h2(f16x2 v, int mask) {
    union { f16x2 h; int i; } u; u.h = v;
    u.i = __shfl_xor(u.i, mask);
    return u.h;
}

// pack softmax weight (f16 bits, sign always 0 -> 15 bits) and src (<2^17)
__device__ __forceinline__ unsigned pack_ws(float w, int src) {
    union { f16x2 h; unsigned u; } t;
    t.h = __builtin_amdgcn_cvt_pkrtz(w, w);
    return (unsigned)src | ((t.u & 0xFFFFu) << 17);
}

// ---------------- CSR build ----------------

// fused: blocks [0,22) swizzle weights into MFMA B-fragment order; rest count.
__global__ void k_prep_count(const float* __restrict__ W1, const float* __restrict__ W2,
                             _Float16* __restrict__ W1Tf, _Float16* __restrict__ W2Tf,
                             const int* __restrict__ dst, int* cnt) {
    if (blockIdx.x < 22) {
        int f = blockIdx.x * 256 + threadIdx.x;
        if (f < 4096) {
            int lane16 = f & 15, quad = (f >> 4) & 3, k0 = (f >> 6) & 3, jt = f >> 8;
            int c = lane16 * 16 + jt;
            int kbase = k0 * 32 + quad * 8;
            _Float16* o = W1Tf + (size_t)f * 8;
            #pragma unroll
            for (int j = 0; j < 8; j++) o[j] = (_Float16)W1[(kbase + j) * HC1c + c];
        } else if (f < 4096 + 1536) {
            int g = f - 4096;
            int lane16 = g & 15, quad = (g >> 4) & 3, k0 = (g >> 6) & 7, jt = g >> 9;
            int c = jt * 16 + lane16;
            int kbase = k0 * 32 + quad * 8;
            _Float16* o = W2Tf + (size_t)g * 8;
            #pragma unroll
            for (int j = 0; j < 8; j++)
                o[j] = (c < NCLSc) ? (_Float16)W2[(kbase + j) * NCLSc + c] : (_Float16)0.f;
        }
    } else {
        int i = (blockIdx.x - 22) * 256 + threadIdx.x;   // 2 edges / thread
        if (i < N_EDGESc / 2) {
            int2 d = ((const int2*)dst)[i];
            atomicAdd(&cnt[d.x], 1);
            atomicAdd(&cnt[d.y], 1);
        }
    }
}

__global__ void k_scan1(const int* __restrict__ cnt, int* rowptr, int* bsums) {
    __shared__ int sh[512];
    int tid = threadIdx.x;
    int i = blockIdx.x * 512 + tid;
    int v = (i < N_NODESc) ? (cnt[i] + 1) : 0;   // +1 = self loop
    sh[tid] = v;
    __syncthreads();
    for (int off = 1; off < 512; off <<= 1) {
        int t = (tid >= off) ? sh[tid - off] : 0;
        __syncthreads();
        sh[tid] += t;
        __syncthreads();
    }
    if (i < N_NODESc) rowptr[i] = sh[tid] - v;   // exclusive within block
    if (tid == 511) bsums[blockIdx.x] = sh[511]; // block TOTAL
}

// scan2 folded in: each block needs exactly one bsums-prefix value P[b>>1]
__global__ void k_scan3(int* rowptr, const int* __restrict__ bsums, int* cursor,
                        int* csr) {
    __shared__ int pref;
    int b = blockIdx.x;
    int need = b >> 1;                  // sum bsums[0..need)
    if (threadIdx.x < 64) {
        int L = threadIdx.x;
        int s = 0;
        for (int j = L; j < need; j += 64) s += bsums[j];
        #pragma unroll
        for (int o = 32; o; o >>= 1) s += __shfl_xor(s, o);
        if (L == 0) pref = s;
    }
    __syncthreads();
    int i = b * 256 + threadIdx.x;
    if (i < N_NODESc) {
        int rp = rowptr[i] + pref;
        rowptr[i] = rp;
        cursor[i] = rp + 1;      // slot rp taken by the self loop
        csr[rp] = i;
    }
    if (i == 0) rowptr[N_NODESc] = E_TOTc;
}

__global__ void k_scatter(const int* __restrict__ src, const int* __restrict__ dst,
                          int* cursor, int* csr) {
    int i = blockIdx.x * blockDim.x + threadIdx.x;   // 2 edges / thread
    if (i < N_EDGESc / 2) {
        int2 s = ((const int2*)src)[i];
        int2 d = ((const int2*)dst)[i];
        int p0 = atomicAdd(&cursor[d.x], 1);
        csr[p0] = s.x;
        int p1 = atomicAdd(&cursor[d.y], 1);
        csr[p1] = s.y;
    }
}

// ---------------- Layer 1 GEMM (MFMA f16): h1 = f16(x) @ W1 ------------------

__global__ __launch_bounds__(256) void k_gemm1(
    const float* __restrict__ x, const _Float16* __restrict__ W1Tf,
    const float* __restrict__ a_src1, const float* __restrict__ a_dst1,
    _Float16* __restrict__ h1, float* __restrict__ as1, float* __restrict__ ad1) {
    int wave = (blockIdx.x * 256 + threadIdx.x) >> 6;
    int n0 = wave * 16;
    if (n0 >= N_NODESc) return;
    int L = threadIdx.x & 63, lane16 = L & 15, quad = L >> 4;
    f32x4 acc[16];
    #pragma unroll
    for (int jt = 0; jt < 16; jt++) acc[jt] = (f32x4){0.f, 0.f, 0.f, 0.f};
    const float* A = x + (size_t)(n0 + lane16) * F_INc + quad * 8;
    const _Float16* Bf = W1Tf + L * 8;
    #pragma unroll
    for (int k0 = 0; k0 < 4; k0++) {                         // K = 4 x 32
        float4 f0 = *(const float4*)(A + k0 * 32);
        float4 f1 = *(const float4*)(A + k0 * 32 + 4);
        union { half8 v; f16x2 h[4]; } af;
        af.h[0] = __builtin_amdgcn_cvt_pkrtz(f0.x, f0.y);
        af.h[1] = __builtin_amdgcn_cvt_pkrtz(f0.z, f0.w);
        af.h[2] = __builtin_amdgcn_cvt_pkrtz(f1.x, f1.y);
        af.h[3] = __builtin_amdgcn_cvt_pkrtz(f1.z, f1.w);
        #pragma unroll
        for (int jt = 0; jt < 16; jt++) {
            half8 bf = *(const half8*)(Bf + (jt * 4 + k0) * 512);
            acc[jt] = __builtin_amdgcn_mfma_f32_16x16x32_f16(af.v, bf, acc[jt], 0, 0, 0);
        }
    }
    // store: row n0+quad*4+r, logical cols lane16*16..+15 (contiguous)
    {
        size_t rowbase = (size_t)(n0 + quad * 4) * HC1c + lane16 * 16;
        #pragma unroll
        for (int r = 0; r < 4; r++) {
            union { uint4 u; f16x2 h[4]; } s0, s1;
            #pragma unroll
            for (int q = 0; q < 4; q++) {
                s0.h[q] = __builtin_amdgcn_cvt_pkrtz(acc[2 * q][r], acc[2 * q + 1][r]);
                s1.h[q] = __builtin_amdgcn_cvt_pkrtz(acc[8 + 2 * q][r], acc[9 + 2 * q][r]);
            }
            *(uint4*)(h1 + rowbase + (size_t)r * HC1c) = s0.u;
            *(uint4*)(h1 + rowbase + (size_t)r * HC1c + 8) = s1.u;
        }
    }
    // alpha epilogue: lane's 16 cols all in head lane16>>1
    {
        float asv[16], adv[16];
        const float4* ap = (const float4*)(a_src1 + lane16 * 16);
        const float4* dp = (const float4*)(a_dst1 + lane16 * 16);
        #pragma unroll
        for (int q = 0; q < 4; q++) {
            float4 a4 = ap[q], d4 = dp[q];
            asv[4*q] = a4.x; asv[4*q+1] = a4.y; asv[4*q+2] = a4.z; asv[4*q+3] = a4.w;
            adv[4*q] = d4.x; adv[4*q+1] = d4.y; adv[4*q+2] = d4.z; adv[4*q+3] = d4.w;
        }
        float ps[4] = {0,0,0,0}, pd[4] = {0,0,0,0};
        #pragma unroll
        for (int jt = 0; jt < 16; jt++) {
            #pragma unroll
            for (int r = 0; r < 4; r++) {
                ps[r] += acc[jt][r] * asv[jt];
                pd[r] += acc[jt][r] * adv[jt];
            }
        }
        #pragma unroll
        for (int r = 0; r < 4; r++) {
            ps[r] += __shfl_xor(ps[r], 1);
            pd[r] += __shfl_xor(pd[r], 1);
        }
        if ((lane16 & 1) == 0) {
            int h = lane16 >> 1;
            #pragma unroll
            for (int r = 0; r < 4; r++) {
                int n = n0 + quad * 4 + r;
                as1[n * 8 + h] = ps[r];
                ad1[n * 8 + h] = pd[r];
            }
        }
    }
}

// ---------------- Layer 1 aggregation: wave-per-node, batched-MLP gather -----
// Phase 1: lane (eL=L>>3, hL=L&7) scores edges eL, eL+8 for head hL; weight+src
// packed into one int -> single ds_bpermute per edge in the gather.
// Gather: half = L>>5 picks edge in pair, l32 = L&31 owns 8 ch, head hA=l32>>2.

__global__ __launch_bounds__(256) void k_agg1(
    const int* __restrict__ rowptr, const int* __restrict__ csr,
    const float* __restrict__ as1, const float* __restrict__ ad1,
    const _Float16* __restrict__ h1, const float* __restrict__ b1,
    _Float16* __restrict__ act1b) {
    int n = blockIdx.x * 4 + (threadIdx.x >> 6);
    if (n >= N_NODESc) return;
    int L = threadIdx.x & 63;
    int eL = L >> 3, hL = L & 7;
    int half = L >> 5, l32 = L & 31;
    int hA = l32 >> 2;
    int beg = rowptr[n], end = rowptr[n + 1];
    float ad = ad1[n * 8 + hL];
    float m_run = -INFINITY, d_run = 0.f;
    f16x2 acc4[4];
    #pragma unroll
    for (int q = 0; q < 4; q++) acc4[q] = (f16x2){(__fp16)0.f, (__fp16)0.f};
    for (int base = beg; base < end; base += 16) {
        int m = min(16, end - base);
        int src0 = 0, src1 = 0;
        float s0 = -INFINITY, s1 = -INFINITY;
        if (eL < m) {
            src0 = csr[base + eL];
            float v = as1[src0 * 8 + hL] + ad;
            s0 = (v > 0.f) ? v : NEG_SLOPEc * v;
        }
        if (eL + 8 < m) {
            src1 = csr[base + eL + 8];
            float v = as1[src1 * 8 + hL] + ad;
            s1 = (v > 0.f) ? v : NEG_SLOPEc * v;
        }
        float mc = fmaxf(s0, s1);
        mc = fmaxf(mc, __shfl_xor(mc, 8));
        mc = fmaxf(mc, __shfl_xor(mc, 16));
        mc = fmaxf(mc, __shfl_xor(mc, 32));
        float mnew = fmaxf(m_run, mc);
        float w0 = (eL < m) ? __expf(s0 - mnew) : 0.f;
        float w1 = (eL + 8 < m) ? __expf(s1 - mnew) : 0.f;
        float wsum = w0 + w1;
        wsum += __shfl_xor(wsum, 8);
        wsum += __shfl_xor(wsum, 16);
        wsum += __shfl_xor(wsum, 32);
        float scale = __expf(m_run - mnew);   // first chunk: 0, acc already 0
        d_run = d_run * scale + wsum;
        m_run = mnew;
        float sc = __shfl(scale, hA);
        f16x2 sc2 = __builtin_amdgcn_cvt_pkrtz(sc, sc);
        #pragma unroll
        for (int q = 0; q < 4; q++) acc4[q] *= sc2;
        unsigned pk0 = pack_ws(w0, src0);
        unsigned pk1 = pack_ws(w1, src1);
        // group A: edges 0..7 (batched loads, then FMAs)
        {
            unsigned pe[4]; uint4 ld[4];
            #pragma unroll
            for (int j = 0; j < 4; j++)
                pe[j] = __shfl(pk0, (2 * j + half) * 8 + hA);
            #pragma unroll
            for (int j = 0; j < 4; j++) {
                int e = 2 * j + half;
                ld[j] = (uint4){0u, 0u, 0u, 0u};
                if (e < m)
                    ld[j] = *((const uint4*)(h1 + (size_t)(pe[j] & 0x1FFFFu) * HC1c) + l32);
            }
            #pragma unroll
            for (int j = 0; j < 4; j++) {
                unsigned hb = pe[j] >> 17;
                union { unsigned u; f16x2 h; } wu; wu.u = hb | (hb << 16);
                union { uint4 u; f16x2 h[4]; } pp; pp.u = ld[j];
                acc4[0] += wu.h * pp.h[0];
                acc4[1] += wu.h * pp.h[1];
                acc4[2] += wu.h * pp.h[2];
                acc4[3] += wu.h * pp.h[3];
            }
        }
        // group B: edges 8..15 (wave-uniform skip)
        if (m > 8) {
            unsigned pe[4]; uint4 ld[4];
            #pragma unroll
            for (int j = 0; j < 4; j++)
                pe[j] = __shfl(pk1, (2 * j + half) * 8 + hA);
            #pragma unroll
            for (int j = 0; j < 4; j++) {
                int e = 8 + 2 * j + half;
                ld[j] = (uint4){0u, 0u, 0u, 0u};
                if (e < m)
                    ld[j] = *((const uint4*)(h1 + (size_t)(pe[j] & 0x1FFFFu) * HC1c) + l32);
            }
            #pragma unroll
            for (int j = 0; j < 4; j++) {
                unsigned hb = pe[j] >> 17;
                union { unsigned u; f16x2 h; } wu; wu.u = hb | (hb << 16);
                union { uint4 u; f16x2 h[4]; } pp; pp.u = ld[j];
                acc4[0] += wu.h * pp.h[0];
                acc4[1] += wu.h * pp.h[1];
                acc4[2] += wu.h * pp.h[2];
                acc4[3] += wu.h * pp.h[3];
            }
        }
    }
    float inv = 1.f / (d_run + 1e-16f);
    float inv_h = __shfl(inv, hA);
    #pragma unroll
    for (int q = 0; q < 4; q++) acc4[q] += shfl_xor_h2(acc4[q], 32);
    if (half == 0) {
        float4 b0 = ((const float4*)b1)[l32 * 2];
        float4 b4 = ((const float4*)b1)[l32 * 2 + 1];
        float o[8];
        o[0] = (float)acc4[0][0] * inv_h + b0.x; o[1] = (float)acc4[0][1] * inv_h + b0.y;
        o[2] = (float)acc4[1][0] * inv_h + b0.z; o[3] = (float)acc4[1][1] * inv_h + b0.w;
        o[4] = (float)acc4[2][0] * inv_h + b4.x; o[5] = (float)acc4[2][1] * inv_h + b4.y;
        o[6] = (float)acc4[3][0] * inv_h + b4.z; o[7] = (float)acc4[3][1] * inv_h + b4.w;
        #pragma unroll
        for (int j = 0; j < 8; j++) o[j] = (o[j] > 0.f) ? o[j] : expm1f(o[j]);
        union { uint4 u; f16x2 h[4]; } st;
        st.h[0] = __builtin_amdgcn_cvt_pkrtz(o[0], o[1]);
        st.h[1] = __builtin_amdgcn_cvt_pkrtz(o[2], o[3]);
        st.h[2] = __builtin_amdgcn_cvt_pkrtz(o[4], o[5]);
        st.h[3] = __builtin_amdgcn_cvt_pkrtz(o[6], o[7]);
        *((uint4*)(act1b + (size_t)n * HC1c) + l32) = st.u;
    }
}

// ---------------- Layer 2 GEMM (MFMA f16) + fused alpha2; h2 out = fp16 ------

__global__ __launch_bounds__(256) void k_gemm2(
    const _Float16* __restrict__ act1b, const _Float16* __restrict__ W2Tf,
    const float* __restrict__ a_src2, const float* __restrict__ a_dst2,
    _Float16* __restrict__ h2b, float* __restrict__ as2, float* __restrict__ ad2) {
    int wave = (blockIdx.x * 256 + threadIdx.x) >> 6;
    int n0 = wave * 16;
    if (n0 >= N_NODESc) return;
    int L = threadIdx.x & 63, lane16 = L & 15, quad = L >> 4;
    f32x4 acc[3];
    #pragma unroll
    for (int jt = 0; jt < 3; jt++) acc[jt] = (f32x4){0.f, 0.f, 0.f, 0.f};
    const _Float16* A = act1b + (size_t)(n0 + lane16) * HC1c + quad * 8;
    const _Float16* Bf = W2Tf + L * 8;
    #pragma unroll
    for (int k0 = 0; k0 < 8; k0++) {                         // K = 8 x 32
        half8 af = *(const half8*)(A + k0 * 32);
        #pragma unroll
        for (int jt = 0; jt < 3; jt++) {
            half8 bf = *(const half8*)(Bf + (jt * 8 + k0) * 512);
            acc[jt] = __builtin_amdgcn_mfma_f32_16x16x32_f16(af, bf, acc[jt], 0, 0, 0);
        }
    }
    float ps[4] = {0.f, 0.f, 0.f, 0.f}, pd[4] = {0.f, 0.f, 0.f, 0.f};
    #pragma unroll
    for (int jt = 0; jt < 3; jt++) {
        int col = jt * 16 + lane16;
        float ws = (col < NCLSc) ? a_src2[col] : 0.f;
        float wd = (col < NCLSc) ? a_dst2[col] : 0.f;
        #pragma unroll
        for (int r = 0; r < 4; r++) {
            float v = acc[jt][r];
            int n = n0 + quad * 4 + r;
            if (col < NCLSc) h2b[(size_t)n * NCLSc + col] = (_Float16)v;
            ps[r] += v * ws; pd[r] += v * wd;
        }
    }
    #pragma unroll
    for (int r = 0; r < 4; r++) {
        float s = ps[r], d = pd[r];
        s += __shfl_xor(s, 1); d += __shfl_xor(d, 1);
        s += __shfl_xor(s, 2); d += __shfl_xor(d, 2);
        s += __shfl_xor(s, 4); d += __shfl_xor(d, 4);
        s += __shfl_xor(s, 8); d += __shfl_xor(d, 8);
        if (lane16 == 0) {
            int n = n0 + quad * 4 + r;
            as2[n] = s; ad2[n] = d;
        }
    }
}

// ---------------- Layer 2 aggregation + bias + log_softmax: wave-per-node ----
// First chunk peeled (deg<=64: essentially all nodes).

__global__ __launch_bounds__(256) void k_agg2(
    const int* __restrict__ rowptr, const int* __restrict__ csr,
    const float* __restrict__ as2, const float* __restrict__ ad2,
    const _Float16* __restrict__ h2b, const float* __restrict__ b2,
    float* __restrict__ out) {
    int n = blockIdx.x * 4 + (threadIdx.x >> 6);
    if (n >= N_NODESc) return;
    int L = threadIdx.x & 63;
    int g = L / 20, cls = L % 20;        // g==3 for lanes 60..63 (gather-idle)
    int beg = rowptr[n], end = rowptr[n + 1];
    float ad = ad2[n];
    float m_run, d_run;
    f16x2 acc2 = (f16x2){(__fp16)0.f, (__fp16)0.f};
    {
        int m = min(64, end - beg);
        int src = 0; float s = -INFINITY;
        if (L < m) {
            src = csr[beg + L];
            float v = as2[src] + ad;
            s = (v > 0.f) ? v : NEG_SLOPEc * v;
        }
        float mc = s;
        for (int o = 32; o; o >>= 1) mc = fmaxf(mc, __shfl_xor(mc, o));
        float w = (L < m) ? __expf(s - mc) : 0.f;
        float ws = w;
        for (int o = 32; o; o >>= 1) ws += __shfl_xor(ws, o);
        m_run = mc; d_run = ws;
        for (int j = 0; j < m; j += 3) {
            int e = j + g;
            int lane = (e < 64) ? e : 63;
            float we = __shfl(w, lane);
            int  se = __shfl(src, lane);
            if (g < 3 && e < m) {
                f16x2 we2 = __builtin_amdgcn_cvt_pkrtz(we, we);
                union { unsigned u; f16x2 h; } pk;
                pk.u = *((const unsigned*)(h2b + (size_t)se * NCLSc) + cls);
                acc2 += we2 * pk.h;
            }
        }
    }
    for (int base = beg + 64; base < end; base += 64) {
        int m = min(64, end - base);
        int src = 0; float s = -INFINITY;
        if (L < m) {
            src = csr[base + L];
            float v = as2[src] + ad;
            s = (v > 0.f) ? v : NEG_SLOPEc * v;
        }
        float mc = s;
        for (int o = 32; o; o >>= 1) mc = fmaxf(mc, __shfl_xor(mc, o));
        float mnew = fmaxf(m_run, mc);
        float w = (L < m) ? __expf(s - mnew) : 0.f;
        float ws = w;
        for (int o = 32; o; o >>= 1) ws += __shfl_xor(ws, o);
        float scale = __expf(m_run - mnew);
        d_run = d_run * scale + ws;
        m_run = mnew;
        f16x2 sc2 = __builtin_amdgcn_cvt_pkrtz(scale, scale);
        acc2 *= sc2;
        for (int j = 0; j < m; j += 3) {
            int e = j + g;
            int lane = (e < 64) ? e : 63;
            float we = __shfl(w, lane);
            int  se = __shfl(src, lane);
            if (g < 3 && e < m) {
                f16x2 we2 = __builtin_amdgcn_cvt_pkrtz(we, we);
                union { unsigned u; f16x2 h; } pk;
                pk.u = *((const unsigned*)(h2b + (size_t)se * NCLSc) + cls);
                acc2 += we2 * pk.h;
            }
        }
    }
    union { f16x2 h; int i; } au; au.h = acc2;
    int i1 = __shfl(au.i, (L + 20) & 63);
    int i2 = __shfl(au.i, (L + 40) & 63);
    union { int i; f16x2 h; } b1u, b2u; b1u.i = i1; b2u.i = i2;
    acc2 = acc2 + b1u.h + b2u.h;
    float vx = -INFINITY, vy = -INFINITY;
    if (L < 20) {
        float2 bb = ((const float2*)b2)[L];
        float inv = 1.f / (d_run + 1e-16f);
        vx = (float)acc2[0] * inv + bb.x;
        vy = (float)acc2[1] * inv + bb.y;
    }
    float mv = fmaxf(vx, vy);
    for (int o = 32; o; o >>= 1) mv = fmaxf(mv, __shfl_xor(mv, o));
    float ex = (L < 20) ? __expf(vx - mv) + __expf(vy - mv) : 0.f;
    for (int o = 32; o; o >>= 1) ex += __shfl_xor(ex, o);
    float ls = logf(ex);
    if (L < 20) {
        float2 o2; o2.x = vx - mv - ls; o2.y = vy - mv - ls;
        ((float2*)(out + (size_t)n * NCLSc))[L] = o2;
    }
}

// ---------------- launch ----------------

extern "C" void kernel_launch(void* const* d_in, const int* in_sizes, int n_in,
                              void* d_out, int out_size, void* d_ws, size_t ws_size,
                              hipStream_t stream) {
    const float* x    = (const float*)d_in[0];
    const int*   ei   = (const int*)d_in[1];
    const float* W1   = (const float*)d_in[2];
    const float* as1w = (const float*)d_in[3];
    const float* ad1w = (const float*)d_in[4];
    const float* b1   = (const float*)d_in[5];
    const float* W2   = (const float*)d_in[6];
    const float* as2w = (const float*)d_in[7];
    const float* ad2w = (const float*)d_in[8];
    const float* b2   = (const float*)d_in[9];
    float* out = (float*)d_out;

    char* p = (char*)d_ws;
    _Float16* h1    = (_Float16*)p; p += (size_t)N_NODESc * HC1c * 2;
    _Float16* act1b = (_Float16*)p; p += (size_t)N_NODESc * HC1c * 2;
    _Float16* W1Tf  = (_Float16*)p; p += (size_t)4096 * 8 * 2;   // 64 KB
    _Float16* W2Tf  = (_Float16*)p; p += (size_t)1536 * 8 * 2;   // 24 KB
    float* a_s1 = (float*)p; p += (size_t)N_NODESc * 8 * 4;
    float* a_d1 = (float*)p; p += (size_t)N_NODESc * 8 * 4;
    _Float16* h2b = (_Float16*)p; p += (size_t)N_NODESc * NCLSc * 2;
    float* a_s2 = (float*)p; p += (size_t)N_NODESc * 4;
    float* a_d2 = (float*)p; p += (size_t)N_NODESc * 4;
    int* rowptr = (int*)p;   p += (size_t)(N_NODESc + 1) * 4;
    int* cursor = (int*)p;   p += (size_t)N_NODESc * 4;
    int* bsums  = (int*)p;   p += 512 * 4;
    int* csr    = (int*)p;   p += (size_t)E_TOTc * 4;
    (void)ws_size; (void)in_sizes; (void)n_in; (void)out_size;

    const int* src = ei;
    const int* dst = ei + N_EDGESc;

    // CSR build (self loops folded into scan; cursor doubles as count buffer)
    (void)hipMemsetAsync(cursor, 0, (size_t)N_NODESc * 4, stream);
    k_prep_count<<<22 + (N_EDGESc / 2 + 255) / 256, 256, 0, stream>>>(
        W1, W2, W1Tf, W2Tf, dst, cursor);
    int nb = (N_NODESc + 511) / 512;
    k_scan1<<<nb, 512, 0, stream>>>(cursor, rowptr, bsums);
    k_scan3<<<(N_NODESc + 255) / 256, 256, 0, stream>>>(rowptr, bsums, cursor, csr);
    k_scatter<<<(N_EDGESc / 2 + 255) / 256, 256, 0, stream>>>(src, dst, cursor, csr);

    int nwave_blk = ((N_NODESc + 15) / 16 + 3) / 4;          // 1563
    k_gemm1<<<nwave_blk, 256, 0, stream>>>(x, W1Tf, as1w, ad1w, h1, a_s1, a_d1);
    k_agg1<<<(N_NODESc + 3) / 4, 256, 0, stream>>>(rowptr, csr, a_s1, a_d1, h1, b1, act1b);
    k_gemm2<<<nwave_blk, 256, 0, stream>>>(act1b, W2Tf, as2w, ad2w, h2b, a_s2, a_d2);
    k_agg2<<<(N_NODESc + 3) / 4, 256, 0, stream>>>(rowptr, csr, a_s2, a_d2, h2b, b2, out);
}

// Round 11
// 358.773 us; speedup vs baseline: 1.0849x; 1.0437x over previous
//
#include <hip/hip_runtime.h>
#include <hip/hip_fp16.h>
#include <math.h>

#define N_NODESc 100000
#define N_EDGESc 800000
#define E_TOTc   (N_EDGESc + N_NODESc)   // 900000, includes self loops
#define F_INc    128
#define HC1c     256                      // H1*C1
#define NCLSc    40
#define NEG_SLOPEc 0.2f

typedef _Float16 half8 __attribute__((ext_vector_type(8)));   // MFMA A/B frag
typedef __fp16   f16x2 __attribute__((ext_vector_type(2)));   // v_pk_* / cvt_pkrtz
typedef float    f32x4 __attribute__((ext_vector_type(4)));

// pack softmax weight (f16 bits, sign always 0 -> 15 bits) and src (<2^17)
__device__ __forceinline__ unsigned pack_ws(float w, int src) {
    union { f16x2 h; unsigned u; } t;
    t.h = __builtin_amdgcn_cvt_pkrtz(w, w);
    return (unsigned)src | ((t.u & 0xFFFFu) << 17);
}
__device__ __forceinline__ float unpack_w(unsigned pe) {
    union { unsigned short s; __fp16 h; } t;
    t.s = (unsigned short)(pe >> 17);
    return (float)t.h;
}

// ---------------- CSR build ----------------

// fused: blocks [0,22) swizzle weights into MFMA B-fragment order; rest count.
__global__ void k_prep_count(const float* __restrict__ W1, const float* __restrict__ W2,
                             _Float16* __restrict__ W1Tf, _Float16* __restrict__ W2Tf,
                             const int* __restrict__ dst, int* cnt) {
    if (blockIdx.x < 22) {
        int f = blockIdx.x * 256 + threadIdx.x;
        if (f < 4096) {
            int lane16 = f & 15, quad = (f >> 4) & 3, k0 = (f >> 6) & 3, jt = f >> 8;
            int c = lane16 * 16 + jt;
            int kbase = k0 * 32 + quad * 8;
            _Float16* o = W1Tf + (size_t)f * 8;
            #pragma unroll
            for (int j = 0; j < 8; j++) o[j] = (_Float16)W1[(kbase + j) * HC1c + c];
        } else if (f < 4096 + 1536) {
            int g = f - 4096;
            int lane16 = g & 15, quad = (g >> 4) & 3, k0 = (g >> 6) & 7, jt = g >> 9;
            int c = jt * 16 + lane16;
            int kbase = k0 * 32 + quad * 8;
            _Float16* o = W2Tf + (size_t)g * 8;
            #pragma unroll
            for (int j = 0; j < 8; j++)
                o[j] = (c < NCLSc) ? (_Float16)W2[(kbase + j) * NCLSc + c] : (_Float16)0.f;
        }
    } else {
        int i = (blockIdx.x - 22) * 256 + threadIdx.x;   // 2 edges / thread
        if (i < N_EDGESc / 2) {
            int2 d = ((const int2*)dst)[i];
            atomicAdd(&cnt[d.x], 1);
            atomicAdd(&cnt[d.y], 1);
        }
    }
}

__global__ void k_scan1(const int* __restrict__ cnt, int* rowptr, int* bsums) {
    __shared__ int sh[512];
    int tid = threadIdx.x;
    int i = blockIdx.x * 512 + tid;
    int v = (i < N_NODESc) ? (cnt[i] + 1) : 0;   // +1 = self loop
    sh[tid] = v;
    __syncthreads();
    for (int off = 1; off < 512; off <<= 1) {
        int t = (tid >= off) ? sh[tid - off] : 0;
        __syncthreads();
        sh[tid] += t;
        __syncthreads();
    }
    if (i < N_NODESc) rowptr[i] = sh[tid] - v;   // exclusive within block
    if (tid == 511) bsums[blockIdx.x] = sh[511]; // block TOTAL
}

// scan2 folded in: each block needs exactly one bsums-prefix value
__global__ void k_scan3(int* rowptr, const int* __restrict__ bsums, int* cursor,
                        int* csr) {
    __shared__ int pref;
    int b = blockIdx.x;
    int need = b >> 1;                  // sum bsums[0..need)
    if (threadIdx.x < 64) {
        int L = threadIdx.x;
        int s = 0;
        for (int j = L; j < need; j += 64) s += bsums[j];
        #pragma unroll
        for (int o = 32; o; o >>= 1) s += __shfl_xor(s, o);
        if (L == 0) pref = s;
    }
    __syncthreads();
    int i = b * 256 + threadIdx.x;
    if (i < N_NODESc) {
        int rp = rowptr[i] + pref;
        rowptr[i] = rp;
        cursor[i] = rp + 1;      // slot rp taken by the self loop
        csr[rp] = i;
    }
    if (i == 0) rowptr[N_NODESc] = E_TOTc;
}

__global__ void k_scatter(const int* __restrict__ src, const int* __restrict__ dst,
                          int* cursor, int* csr) {
    int i = blockIdx.x * blockDim.x + threadIdx.x;   // 4 edges / thread
    if (i < N_EDGESc / 4) {
        int4 s = ((const int4*)src)[i];
        int4 d = ((const int4*)dst)[i];
        int p0 = atomicAdd(&cursor[d.x], 1); csr[p0] = s.x;
        int p1 = atomicAdd(&cursor[d.y], 1); csr[p1] = s.y;
        int p2 = atomicAdd(&cursor[d.z], 1); csr[p2] = s.z;
        int p3 = atomicAdd(&cursor[d.w], 1); csr[p3] = s.w;
    }
}

// ---------------- Layer 1 GEMM (MFMA f16): h1 = f16(x) @ W1, fp8 out ---------

__global__ __launch_bounds__(256) void k_gemm1(
    const float* __restrict__ x, const _Float16* __restrict__ W1Tf,
    const float* __restrict__ a_src1, const float* __restrict__ a_dst1,
    unsigned char* __restrict__ h1f8, float* __restrict__ as1, float* __restrict__ ad1) {
    int wave = (blockIdx.x * 256 + threadIdx.x) >> 6;
    int n0 = wave * 16;
    if (n0 >= N_NODESc) return;
    int L = threadIdx.x & 63, lane16 = L & 15, quad = L >> 4;
    f32x4 acc[16];
    #pragma unroll
    for (int jt = 0; jt < 16; jt++) acc[jt] = (f32x4){0.f, 0.f, 0.f, 0.f};
    const float* A = x + (size_t)(n0 + lane16) * F_INc + quad * 8;
    const _Float16* Bf = W1Tf + L * 8;
    #pragma unroll
    for (int k0 = 0; k0 < 4; k0++) {                         // K = 4 x 32
        float4 f0 = *(const float4*)(A + k0 * 32);
        float4 f1 = *(const float4*)(A + k0 * 32 + 4);
        union { half8 v; f16x2 h[4]; } af;
        af.h[0] = __builtin_amdgcn_cvt_pkrtz(f0.x, f0.y);
        af.h[1] = __builtin_amdgcn_cvt_pkrtz(f0.z, f0.w);
        af.h[2] = __builtin_amdgcn_cvt_pkrtz(f1.x, f1.y);
        af.h[3] = __builtin_amdgcn_cvt_pkrtz(f1.z, f1.w);
        #pragma unroll
        for (int jt = 0; jt < 16; jt++) {
            half8 bf = *(const half8*)(Bf + (jt * 4 + k0) * 512);
            acc[jt] = __builtin_amdgcn_mfma_f32_16x16x32_f16(af.v, bf, acc[jt], 0, 0, 0);
        }
    }
    // store fp8: row n0+quad*4+r, logical cols lane16*16..+15 = 16 B contiguous
    {
        #pragma unroll
        for (int r = 0; r < 4; r++) {
            uint4 st;
            int d;
            d = __builtin_amdgcn_cvt_pk_fp8_f32(acc[0][r], acc[1][r], 0, false);
            d = __builtin_amdgcn_cvt_pk_fp8_f32(acc[2][r], acc[3][r], d, true);
            st.x = (unsigned)d;
            d = __builtin_amdgcn_cvt_pk_fp8_f32(acc[4][r], acc[5][r], 0, false);
            d = __builtin_amdgcn_cvt_pk_fp8_f32(acc[6][r], acc[7][r], d, true);
            st.y = (unsigned)d;
            d = __builtin_amdgcn_cvt_pk_fp8_f32(acc[8][r], acc[9][r], 0, false);
            d = __builtin_amdgcn_cvt_pk_fp8_f32(acc[10][r], acc[11][r], d, true);
            st.z = (unsigned)d;
            d = __builtin_amdgcn_cvt_pk_fp8_f32(acc[12][r], acc[13][r], 0, false);
            d = __builtin_amdgcn_cvt_pk_fp8_f32(acc[14][r], acc[15][r], d, true);
            st.w = (unsigned)d;
            *(uint4*)(h1f8 + (size_t)(n0 + quad * 4 + r) * HC1c + lane16 * 16) = st;
        }
    }
    // alpha epilogue: lane's 16 cols all in head lane16>>1
    {
        float asv[16], adv[16];
        const float4* ap = (const float4*)(a_src1 + lane16 * 16);
        const float4* dp = (const float4*)(a_dst1 + lane16 * 16);
        #pragma unroll
        for (int q = 0; q < 4; q++) {
            float4 a4 = ap[q], d4 = dp[q];
            asv[4*q] = a4.x; asv[4*q+1] = a4.y; asv[4*q+2] = a4.z; asv[4*q+3] = a4.w;
            adv[4*q] = d4.x; adv[4*q+1] = d4.y; adv[4*q+2] = d4.z; adv[4*q+3] = d4.w;
        }
        float ps[4] = {0,0,0,0}, pd[4] = {0,0,0,0};
        #pragma unroll
        for (int jt = 0; jt < 16; jt++) {
            #pragma unroll
            for (int r = 0; r < 4; r++) {
                ps[r] += acc[jt][r] * asv[jt];
                pd[r] += acc[jt][r] * adv[jt];
            }
        }
        #pragma unroll
        for (int r = 0; r < 4; r++) {
            ps[r] += __shfl_xor(ps[r], 1);
            pd[r] += __shfl_xor(pd[r], 1);
        }
        if ((lane16 & 1) == 0) {
            int h = lane16 >> 1;
            #pragma unroll
            for (int r = 0; r < 4; r++) {
                int n = n0 + quad * 4 + r;
                as1[n * 8 + h] = ps[r];
                ad1[n * 8 + h] = pd[r];
            }
        }
    }
}

// ---------------- Layer 1 aggregation: wave-per-node, fp8 gather -------------
// Phase 1: lane (eL=L>>3, hL=L&7) scores edges eL, eL+8; packed (w|src).
// Gather: all 64 lanes per edge; lane L owns ch 4L..4L+3 (head hA=L>>3),
// 1 dword fp8 load + 2 cvt + 4 f32 FMA per edge; 4 edges batched per round.

__global__ __launch_bounds__(256) void k_agg1(
    const int* __restrict__ rowptr, const int* __restrict__ csr,
    const float* __restrict__ as1, const float* __restrict__ ad1,
    const unsigned char* __restrict__ h1f8, const float* __restrict__ b1,
    _Float16* __restrict__ act1b) {
    int n = blockIdx.x * 4 + (threadIdx.x >> 6);
    if (n >= N_NODESc) return;
    int L = threadIdx.x & 63;
    int eL = L >> 3, hL = L & 7;
    int hA = L >> 3;                  // head of my 4 channels
    int beg = rowptr[n], end = rowptr[n + 1];
    float ad = ad1[n * 8 + hL];
    float m_run = -INFINITY, d_run = 0.f;
    float acc[4] = {0.f, 0.f, 0.f, 0.f};
    for (int base = beg; base < end; base += 16) {
        int m = min(16, end - base);
        int src0 = 0, src1 = 0;
        float s0 = -INFINITY, s1 = -INFINITY;
        if (eL < m) {
            src0 = csr[base + eL];
            float v = as1[src0 * 8 + hL] + ad;
            s0 = (v > 0.f) ? v : NEG_SLOPEc * v;
        }
        if (eL + 8 < m) {
            src1 = csr[base + eL + 8];
            float v = as1[src1 * 8 + hL] + ad;
            s1 = (v > 0.f) ? v : NEG_SLOPEc * v;
        }
        float mc = fmaxf(s0, s1);
        mc = fmaxf(mc, __shfl_xor(mc, 8));
        mc = fmaxf(mc, __shfl_xor(mc, 16));
        mc = fmaxf(mc, __shfl_xor(mc, 32));
        float mnew = fmaxf(m_run, mc);
        float w0 = (eL < m) ? __expf(s0 - mnew) : 0.f;
        float w1 = (eL + 8 < m) ? __expf(s1 - mnew) : 0.f;
        float wsum = w0 + w1;
        wsum += __shfl_xor(wsum, 8);
        wsum += __shfl_xor(wsum, 16);
        wsum += __shfl_xor(wsum, 32);
        float scale = __expf(m_run - mnew);   // first chunk: 0, acc already 0
        d_run = d_run * scale + wsum;
        m_run = mnew;
        float sc = __shfl(scale, hA);
        #pragma unroll
        for (int q = 0; q < 4; q++) acc[q] *= sc;
        unsigned pk0 = pack_ws(w0, src0);
        unsigned pk1 = pack_ws(w1, src1);
        // 4 rounds of 4 edges; loads batched; w==0 kills invalid edges
        #pragma unroll
        for (int r = 0; r < 4; r++) {
            int e0 = r * 4;
            if (e0 < m) {                        // wave-uniform
                unsigned pk = (e0 < 8) ? pk0 : pk1;
                unsigned pe[4]; unsigned ld[4];
                #pragma unroll
                for (int j = 0; j < 4; j++)
                    pe[j] = __shfl(pk, ((e0 + j) & 7) * 8 + hA);
                #pragma unroll
                for (int j = 0; j < 4; j++)
                    ld[j] = *((const unsigned*)(h1f8 + (size_t)(pe[j] & 0x1FFFFu) * HC1c) + L);
                #pragma unroll
                for (int j = 0; j < 4; j++) {
                    float w = unpack_w(pe[j]);
                    auto lo = __builtin_amdgcn_cvt_pk_f32_fp8((int)ld[j], false);
                    auto hi = __builtin_amdgcn_cvt_pk_f32_fp8((int)ld[j], true);
                    acc[0] += w * lo[0];
                    acc[1] += w * lo[1];
                    acc[2] += w * hi[0];
                    acc[3] += w * hi[1];
                }
            }
        }
    }
    float inv = 1.f / (d_run + 1e-16f);
    float inv_h = __shfl(inv, hA);
    float4 bb = ((const float4*)b1)[L];
    float o0 = acc[0] * inv_h + bb.x;
    float o1 = acc[1] * inv_h + bb.y;
    float o2 = acc[2] * inv_h + bb.z;
    float o3 = acc[3] * inv_h + bb.w;
    o0 = (o0 > 0.f) ? o0 : expm1f(o0);
    o1 = (o1 > 0.f) ? o1 : expm1f(o1);
    o2 = (o2 > 0.f) ? o2 : expm1f(o2);
    o3 = (o3 > 0.f) ? o3 : expm1f(o3);
    union { uint2 u; f16x2 h[2]; } st;
    st.h[0] = __builtin_amdgcn_cvt_pkrtz(o0, o1);
    st.h[1] = __builtin_amdgcn_cvt_pkrtz(o2, o3);
    ((uint2*)(act1b + (size_t)n * HC1c))[L] = st.u;
}

// ---------------- Layer 2 GEMM (MFMA f16) + fused alpha2; h2 out = fp16 ------

__global__ __launch_bounds__(256) void k_gemm2(
    const _Float16* __restrict__ act1b, const _Float16* __restrict__ W2Tf,
    const float* __restrict__ a_src2, const float* __restrict__ a_dst2,
    _Float16* __restrict__ h2b, float* __restrict__ as2, float* __restrict__ ad2) {
    int wave = (blockIdx.x * 256 + threadIdx.x) >> 6;
    int n0 = wave * 16;
    if (n0 >= N_NODESc) return;
    int L = threadIdx.x & 63, lane16 = L & 15, quad = L >> 4;
    f32x4 acc[3];
    #pragma unroll
    for (int jt = 0; jt < 3; jt++) acc[jt] = (f32x4){0.f, 0.f, 0.f, 0.f};
    const _Float16* A = act1b + (size_t)(n0 + lane16) * HC1c + quad * 8;
    const _Float16* Bf = W2Tf + L * 8;
    #pragma unroll
    for (int k0 = 0; k0 < 8; k0++) {                         // K = 8 x 32
        half8 af = *(const half8*)(A + k0 * 32);
        #pragma unroll
        for (int jt = 0; jt < 3; jt++) {
            half8 bf = *(const half8*)(Bf + (jt * 8 + k0) * 512);
            acc[jt] = __builtin_amdgcn_mfma_f32_16x16x32_f16(af, bf, acc[jt], 0, 0, 0);
        }
    }
    float ps[4] = {0.f, 0.f, 0.f, 0.f}, pd[4] = {0.f, 0.f, 0.f, 0.f};
    #pragma unroll
    for (int jt = 0; jt < 3; jt++) {
        int col = jt * 16 + lane16;
        float ws = (col < NCLSc) ? a_src2[col] : 0.f;
        float wd = (col < NCLSc) ? a_dst2[col] : 0.f;
        #pragma unroll
        for (int r = 0; r < 4; r++) {
            float v = acc[jt][r];
            int n = n0 + quad * 4 + r;
            if (col < NCLSc) h2b[(size_t)n * NCLSc + col] = (_Float16)v;
            ps[r] += v * ws; pd[r] += v * wd;
        }
    }
    #pragma unroll
    for (int r = 0; r < 4; r++) {
        float s = ps[r], d = pd[r];
        s += __shfl_xor(s, 1); d += __shfl_xor(d, 1);
        s += __shfl_xor(s, 2); d += __shfl_xor(d, 2);
        s += __shfl_xor(s, 4); d += __shfl_xor(d, 4);
        s += __shfl_xor(s, 8); d += __shfl_xor(d, 8);
        if (lane16 == 0) {
            int n = n0 + quad * 4 + r;
            as2[n] = s; ad2[n] = d;
        }
    }
}

// ---------------- Layer 2 aggregation + bias + log_softmax: wave-per-node ----
// Gather: lane group g=L/20 handles edges 9-batched (3 rounds in flight).

__global__ __launch_bounds__(256) void k_agg2(
    const int* __restrict__ rowptr, const int* __restrict__ csr,
    const float* __restrict__ as2, const float* __restrict__ ad2,
    const _Float16* __restrict__ h2b, const float* __restrict__ b2,
    float* __restrict__ out) {
    int n = blockIdx.x * 4 + (threadIdx.x >> 6);
    if (n >= N_NODESc) return;
    int L = threadIdx.x & 63;
    int g = L / 20, cls = L % 20;        // g==3 for lanes 60..63 (results unused)
    int beg = rowptr[n], end = rowptr[n + 1];
    float ad = ad2[n];
    float m_run = -INFINITY, d_run = 0.f;
    f16x2 acc2 = (f16x2){(__fp16)0.f, (__fp16)0.f};
    for (int base = beg; base < end; base += 64) {
        int m = min(64, end - base);
        int src = 0; float s = -INFINITY;
        if (L < m) {
            src = csr[base + L];
            float v = as2[src] + ad;
            s = (v > 0.f) ? v : NEG_SLOPEc * v;
        }
        float mc = s;
        for (int o = 32; o; o >>= 1) mc = fmaxf(mc, __shfl_xor(mc, o));
        float mnew = fmaxf(m_run, mc);
        float w = (L < m) ? __expf(s - mnew) : 0.f;
        float ws = w;
        for (int o = 32; o; o >>= 1) ws += __shfl_xor(ws, o);
        float scale = __expf(m_run - mnew);   // first chunk: 0, acc already 0
        d_run = d_run * scale + ws;
        m_run = mnew;
        f16x2 sc2 = __builtin_amdgcn_cvt_pkrtz(scale, scale);
        acc2 *= sc2;
        for (int jb = 0; jb < m; jb += 9) {   // 3 rounds of 3 groups, batched
            float wv[3]; int sev[3]; unsigned ldv[3];
            #pragma unroll
            for (int r = 0; r < 3; r++) {
                int e = jb + r * 3 + g;
                int lane = (e < 64) ? e : 63;
                wv[r] = __shfl(w, lane);      // 0 for e >= m
                sev[r] = __shfl(src, lane);
            }
            #pragma unroll
            for (int r = 0; r < 3; r++) {
                ldv[r] = 0u;
                if (g < 3)
                    ldv[r] = *((const unsigned*)(h2b + (size_t)sev[r] * NCLSc) + cls);
            }
            #pragma unroll
            for (int r = 0; r < 3; r++) {
                f16x2 we2 = __builtin_amdgcn_cvt_pkrtz(wv[r], wv[r]);
                union { unsigned u; f16x2 h; } pk; pk.u = ldv[r];
                acc2 += we2 * pk.h;
            }
        }
    }
    union { f16x2 h; int i; } au; au.h = acc2;
    int i1 = __shfl(au.i, (L + 20) & 63);
    int i2 = __shfl(au.i, (L + 40) & 63);
    union { int i; f16x2 h; } b1u, b2u; b1u.i = i1; b2u.i = i2;
    acc2 = acc2 + b1u.h + b2u.h;
    float vx = -INFINITY, vy = -INFINITY;
    if (L < 20) {
        float2 bb = ((const float2*)b2)[L];
        float inv = 1.f / (d_run + 1e-16f);
        vx = (float)acc2[0] * inv + bb.x;
        vy = (float)acc2[1] * inv + bb.y;
    }
    float mv = fmaxf(vx, vy);
    for (int o = 32; o; o >>= 1) mv = fmaxf(mv, __shfl_xor(mv, o));
    float ex = (L < 20) ? __expf(vx - mv) + __expf(vy - mv) : 0.f;
    for (int o = 32; o; o >>= 1) ex += __shfl_xor(ex, o);
    float ls = logf(ex);
    if (L < 20) {
        float2 o2; o2.x = vx - mv - ls; o2.y = vy - mv - ls;
        ((float2*)(out + (size_t)n * NCLSc))[L] = o2;
    }
}

// ---------------- launch ----------------

extern "C" void kernel_launch(void* const* d_in, const int* in_sizes, int n_in,
                              void* d_out, int out_size, void* d_ws, size_t ws_size,
                              hipStream_t stream) {
    const float* x    = (const float*)d_in[0];
    const int*   ei   = (const int*)d_in[1];
    const float* W1   = (const float*)d_in[2];
    const float* as1w = (const float*)d_in[3];
    const float* ad1w = (const float*)d_in[4];
    const float* b1   = (const float*)d_in[5];
    const float* W2   = (const float*)d_in[6];
    const float* as2w = (const float*)d_in[7];
    const float* ad2w = (const float*)d_in[8];
    const float* b2   = (const float*)d_in[9];
    float* out = (float*)d_out;

    char* p = (char*)d_ws;
    unsigned char* h1f8 = (unsigned char*)p; p += (size_t)N_NODESc * HC1c;     // 25.6 MB
    _Float16* act1b = (_Float16*)p; p += (size_t)N_NODESc * HC1c * 2;
    _Float16* W1Tf  = (_Float16*)p; p += (size_t)4096 * 8 * 2;   // 64 KB
    _Float16* W2Tf  = (_Float16*)p; p += (size_t)1536 * 8 * 2;   // 24 KB
    float* a_s1 = (float*)p; p += (size_t)N_NODESc * 8 * 4;
    float* a_d1 = (float*)p; p += (size_t)N_NODESc * 8 * 4;
    _Float16* h2b = (_Float16*)p; p += (size_t)N_NODESc * NCLSc * 2;
    float* a_s2 = (float*)p; p += (size_t)N_NODESc * 4;
    float* a_d2 = (float*)p; p += (size_t)N_NODESc * 4;
    int* rowptr = (int*)p;   p += (size_t)(N_NODESc + 1) * 4;
    int* cursor = (int*)p;   p += (size_t)N_NODESc * 4;
    int* bsums  = (int*)p;   p += 512 * 4;
    int* csr    = (int*)p;   p += (size_t)E_TOTc * 4;
    (void)ws_size; (void)in_sizes; (void)n_in; (void)out_size;

    const int* src = ei;
    const int* dst = ei + N_EDGESc;

    // CSR build (self loops folded into scan; cursor doubles as count buffer)
    (void)hipMemsetAsync(cursor, 0, (size_t)N_NODESc * 4, stream);
    k_prep_count<<<22 + (N_EDGESc / 2 + 255) / 256, 256, 0, stream>>>(
        W1, W2, W1Tf, W2Tf, dst, cursor);
    int nb = (N_NODESc + 511) / 512;
    k_scan1<<<nb, 512, 0, stream>>>(cursor, rowptr, bsums);
    k_scan3<<<(N_NODESc + 255) / 256, 256, 0, stream>>>(rowptr, bsums, cursor, csr);
    k_scatter<<<(N_EDGESc / 4 + 255) / 256, 256, 0, stream>>>(src, dst, cursor, csr);

    int nwave_blk = ((N_NODESc + 15) / 16 + 3) / 4;          // 1563
    k_gemm1<<<nwave_blk, 256, 0, stream>>>(x, W1Tf, as1w, ad1w, h1f8, a_s1, a_d1);
    k_agg1<<<(N_NODESc + 3) / 4, 256, 0, stream>>>(rowptr, csr, a_s1, a_d1, h1f8, b1, act1b);
    k_gemm2<<<nwave_blk, 256, 0, stream>>>(act1b, W2Tf, as2w, ad2w, h2b, a_s2, a_d2);
    k_agg2<<<(N_NODESc + 3) / 4, 256, 0, stream>>>(rowptr, csr, a_s2, a_d2, h2b, b2, out);
}